// Round 9
// baseline (334.111 us; speedup 1.0000x reference)
//
#include <hip/hip_runtime.h>
#include <hip/hip_cooperative_groups.h>

namespace cg = cooperative_groups;

#define HW 9216
#define W 96
#define H 96
#define NC 256
#define NT 49
#define NPAIR 25
#define EPSV 1e-5f

#define TS 16
#define HSZ 22
#define CC 8
#define NZ 32

#define OUTS 384
#define SRCP 10

typedef _Float16 half8 __attribute__((ext_vector_type(8)));
typedef _Float16 half2v __attribute__((ext_vector_type(2)));

union SmemU {
    half8 xs[HSZ][HSZ];          // 7744 B
    float cvs[3][SRCP][SRCP];    // 1200 B
};

// ============================ cooperative mega-kernel ========================
__global__ __launch_bounds__(256, 5) void mp_fused(const float* __restrict__ x,
                                                   const float* __restrict__ w,
                                                   const float* __restrict__ cw,
                                                   const float* __restrict__ cb,
                                                   _Float16* x1h,
                                                   float* partial,
                                                   float* __restrict__ out) {
    cg::grid_group grid = cg::this_grid();
    __shared__ SmemU sm;

    const int tx = threadIdx.x & 15;
    const int ty = threadIdx.x >> 4;
    const int bx = blockIdx.x * TS;
    const int by = blockIdx.y * TS;
    const int px = bx + tx;
    const int py = by + ty;
    const int p = py * W + px;
    const int z = blockIdx.z;

    // ---------- phase 1: stage fp32 x (c-major strided) -> fp16 LDS ----------
    const float* __restrict__ xb = x + (size_t)z * CC * HW;
#pragma unroll
    for (int it = 0; it < 2; ++it) {
        const int i = threadIdx.x + it * 256;
        if (i < HSZ * HSZ) {
            const int hy = i / HSZ;
            const int hx = i - hy * HSZ;
            const int gy = by - 3 + hy;
            const int gx = bx - 3 + hx;
            half8 h;
#pragma unroll
            for (int c = 0; c < 8; ++c) h[c] = (_Float16)0.f;
            if ((unsigned)gy < (unsigned)H && (unsigned)gx < (unsigned)W) {
                const float* sp = xb + gy * W + gx;
#pragma unroll
                for (int c = 0; c < 8; ++c) h[c] = (_Float16)sp[c * HW];
            }
            sm.xs[hy][hx] = h;
        }
    }

    // ---------- weights: 2-pass normalize (low register pressure) ------------
    half2v wh[NPAIR];
    {
        float s = 0.f;
#pragma unroll
        for (int t = 0; t < NT; ++t) s += w[t * HW + p];
        const float inv = 1.f / (s + EPSV);
#pragma unroll
        for (int i = 0; i < NPAIR; ++i) {
            const float a = w[(2 * i) * HW + p] * inv;
            const float b = (2 * i + 1 < NT) ? w[(2 * i + 1) * HW + p] * inv : 0.f;
            half2v h;
            h[0] = (_Float16)a;
            h[1] = (_Float16)b;
            wh[i] = h;
        }
    }
    __syncthreads();

    // ---------- phase-1 taps ----------
    {
        float acc[8];
#pragma unroll
        for (int k = 0; k < 8; ++k) acc[k] = 0.f;
#pragma unroll
        for (int i = 0; i < 7; ++i) {
#pragma unroll
            for (int j = 0; j < 7; ++j) {
                const int t = i * 7 + j;
                const float wf = (float)wh[t >> 1][t & 1];
                const half8 v = sm.xs[ty + i][tx + j];
#pragma unroll
                for (int k = 0; k < 8; ++k)
                    acc[k] = fmaf(wf, (float)v[k], acc[k]);
            }
        }
        half8 h1;
#pragma unroll
        for (int k = 0; k < 8; ++k) h1[k] = (_Float16)acc[k];
        *(half8*)(x1h + ((size_t)z * HW + p) * 8) = h1;
    }

    grid.sync();

    // ---------- phase 2: stage x1h halo (packed fp16) ----------
    const _Float16* xz = x1h + (size_t)z * HW * 8;
#pragma unroll
    for (int it = 0; it < 2; ++it) {
        const int i = threadIdx.x + it * 256;
        if (i < HSZ * HSZ) {
            const int hy = i / HSZ;
            const int hx = i - hy * HSZ;
            const int gy = by - 3 + hy;
            const int gx = bx - 3 + hx;
            half8 v;
#pragma unroll
            for (int c = 0; c < 8; ++c) v[c] = (_Float16)0.f;
            if ((unsigned)gy < (unsigned)H && (unsigned)gx < (unsigned)W)
                v = *(const half8*)(xz + (size_t)(gy * W + gx) * 8);
            sm.xs[hy][hx] = v;
        }
    }
    __syncthreads();

    // ---------- phase-2 taps + partial 1x1 conv ----------
    {
        float acc[8];
#pragma unroll
        for (int k = 0; k < 8; ++k) acc[k] = 0.f;
#pragma unroll
        for (int i = 0; i < 7; ++i) {
#pragma unroll
            for (int j = 0; j < 7; ++j) {
                const int t = i * 7 + j;
                const float wf = (float)wh[t >> 1][t & 1];
                const half8 v = sm.xs[ty + i][tx + j];
#pragma unroll
                for (int k = 0; k < 8; ++k)
                    acc[k] = fmaf(wf, (float)v[k], acc[k]);
            }
        }
        float o0 = 0.f, o1 = 0.f, o2 = 0.f;
        const int cbase = z * CC;
#pragma unroll
        for (int k = 0; k < 8; ++k) {
            const int c = cbase + k;
            o0 = fmaf(acc[k], cw[c], o0);
            o1 = fmaf(acc[k], cw[NC + c], o1);
            o2 = fmaf(acc[k], cw[2 * NC + c], o2);
        }
        partial[(z * 3 + 0) * HW + p] = o0;
        partial[(z * 3 + 1) * HW + p] = o1;
        partial[(z * 3 + 2) * HW + p] = o2;
    }

    grid.sync();

    // ---------- phase 3: z-reduce + bias + bilinear upsample (144 blocks) ----
    const int bid = (blockIdx.z * 6 + blockIdx.y) * 6 + blockIdx.x;
    if (bid >= 144) return;
    const int X = (bid % 12) * 32;
    const int Y = (bid / 12) * 32;
    const int x0s = X >> 2;
    const int y0s = Y >> 2;

    for (int e = threadIdx.x; e < 3 * SRCP * SRCP; e += 256) {
        int ch = e / (SRCP * SRCP);
        int r = e - ch * (SRCP * SRCP);
        int sy = r / SRCP;
        int sx = r - sy * SRCP;
        int gy = min(max(y0s - 1 + sy, 0), H - 1);
        int gx = min(max(x0s - 1 + sx, 0), W - 1);
        const int pp = gy * W + gx;
        float sum = cb[ch];
#pragma unroll
        for (int zz = 0; zz < NZ; ++zz) sum += partial[(zz * 3 + ch) * HW + pp];
        sm.cvs[ch][sy][sx] = sum;
    }
    __syncthreads();

    const int xl = threadIdx.x & 31;
    const int yl0 = threadIdx.x >> 5;
    const int xo = X + xl;
    const float sxf = xo * 0.25f - 0.375f;
    const float fxf = floorf(sxf);
    const int jx = (int)fxf - (x0s - 1);
    const float fx = sxf - fxf;

#pragma unroll
    for (int k = 0; k < 4; ++k) {
        const int yo = Y + yl0 + 8 * k;
        const float syf = yo * 0.25f - 0.375f;
        const float fyf = floorf(syf);
        const int jy = (int)fyf - (y0s - 1);
        const float fy = syf - fyf;
#pragma unroll
        for (int ch = 0; ch < 3; ++ch) {
            const float v00 = sm.cvs[ch][jy][jx], v01 = sm.cvs[ch][jy][jx + 1];
            const float v10 = sm.cvs[ch][jy + 1][jx], v11 = sm.cvs[ch][jy + 1][jx + 1];
            const float v0 = v00 + (v01 - v00) * fx;
            const float v1 = v10 + (v11 - v10) * fx;
            out[ch * OUTS * OUTS + yo * OUTS + xo] = v0 + (v1 - v0) * fy;
        }
    }
}

// ============================ fallback path (R7) =============================
__global__ __launch_bounds__(256) void step1_kernel(const float* __restrict__ x,
                                                    const float* __restrict__ w,
                                                    _Float16* __restrict__ x1h,
                                                    half2v* __restrict__ nwh) {
    __shared__ half8 xs[HSZ][HSZ];
    const int tx = threadIdx.x & 15;
    const int ty = threadIdx.x >> 4;
    const int bx = blockIdx.x * TS;
    const int by = blockIdx.y * TS;
    const int px = bx + tx;
    const int py = by + ty;
    const int p = py * W + px;
    const int z = blockIdx.z;

    const float* __restrict__ xb = x + (size_t)z * CC * HW;
#pragma unroll
    for (int it = 0; it < 2; ++it) {
        const int i = threadIdx.x + it * 256;
        if (i < HSZ * HSZ) {
            const int hy = i / HSZ;
            const int hx = i - hy * HSZ;
            const int gy = by - 3 + hy;
            const int gx = bx - 3 + hx;
            half8 h;
#pragma unroll
            for (int c = 0; c < 8; ++c) h[c] = (_Float16)0.f;
            if ((unsigned)gy < (unsigned)H && (unsigned)gx < (unsigned)W) {
                const float* sp = xb + gy * W + gx;
#pragma unroll
                for (int c = 0; c < 8; ++c) h[c] = (_Float16)sp[c * HW];
            }
            xs[hy][hx] = h;
        }
    }

    float wreg[NT];
    float s = 0.f;
#pragma unroll
    for (int t = 0; t < NT; ++t) { wreg[t] = w[t * HW + p]; s += wreg[t]; }
    const float inv = 1.f / (s + EPSV);
#pragma unroll
    for (int t = 0; t < NT; ++t) wreg[t] *= inv;

    if (z == 0) {
#pragma unroll
        for (int i = 0; i < NPAIR; ++i) {
            half2v h;
            h[0] = (_Float16)wreg[2 * i];
            h[1] = (2 * i + 1 < NT) ? (_Float16)wreg[2 * i + 1] : (_Float16)0.f;
            nwh[i * HW + p] = h;
        }
    }
    __syncthreads();

    float acc[8];
#pragma unroll
    for (int k = 0; k < 8; ++k) acc[k] = 0.f;
#pragma unroll
    for (int i = 0; i < 7; ++i) {
#pragma unroll
        for (int j = 0; j < 7; ++j) {
            const float wf = wreg[i * 7 + j];
            const half8 v = xs[ty + i][tx + j];
#pragma unroll
            for (int k = 0; k < 8; ++k)
                acc[k] = fmaf(wf, (float)v[k], acc[k]);
        }
    }
    half8 h;
#pragma unroll
    for (int k = 0; k < 8; ++k) h[k] = (_Float16)acc[k];
    *(half8*)(x1h + ((size_t)z * HW + p) * 8) = h;
}

__global__ __launch_bounds__(256) void step2_kernel(const _Float16* __restrict__ xin,
                                                    const half2v* __restrict__ nwh,
                                                    const float* __restrict__ cw,
                                                    float* __restrict__ partial) {
    __shared__ half8 xs[HSZ][HSZ];
    const int tx = threadIdx.x & 15;
    const int ty = threadIdx.x >> 4;
    const int bx = blockIdx.x * TS;
    const int by = blockIdx.y * TS;
    const int px = bx + tx;
    const int py = by + ty;
    const int p = py * W + px;
    const int z = blockIdx.z;

    const _Float16* __restrict__ xz = xin + (size_t)z * HW * 8;
#pragma unroll
    for (int it = 0; it < 2; ++it) {
        const int i = threadIdx.x + it * 256;
        if (i < HSZ * HSZ) {
            const int hy = i / HSZ;
            const int hx = i - hy * HSZ;
            const int gy = by - 3 + hy;
            const int gx = bx - 3 + hx;
            half8 v;
#pragma unroll
            for (int c = 0; c < 8; ++c) v[c] = (_Float16)0.f;
            if ((unsigned)gy < (unsigned)H && (unsigned)gx < (unsigned)W)
                v = *(const half8*)(xz + (size_t)(gy * W + gx) * 8);
            xs[hy][hx] = v;
        }
    }

    half2v wu[NPAIR];
#pragma unroll
    for (int i = 0; i < NPAIR; ++i) wu[i] = nwh[i * HW + p];
    __syncthreads();

    float acc[8];
#pragma unroll
    for (int k = 0; k < 8; ++k) acc[k] = 0.f;
#pragma unroll
    for (int i = 0; i < 7; ++i) {
#pragma unroll
        for (int j = 0; j < 7; ++j) {
            const int t = i * 7 + j;
            const float wf = (float)wu[t >> 1][t & 1];
            const half8 v = xs[ty + i][tx + j];
#pragma unroll
            for (int k = 0; k < 8; ++k)
                acc[k] = fmaf(wf, (float)v[k], acc[k]);
        }
    }

    float o0 = 0.f, o1 = 0.f, o2 = 0.f;
    const int cbase = z * CC;
#pragma unroll
    for (int k = 0; k < 8; ++k) {
        const int c = cbase + k;
        o0 = fmaf(acc[k], cw[c], o0);
        o1 = fmaf(acc[k], cw[NC + c], o1);
        o2 = fmaf(acc[k], cw[2 * NC + c], o2);
    }
    partial[(z * 3 + 0) * HW + p] = o0;
    partial[(z * 3 + 1) * HW + p] = o1;
    partial[(z * 3 + 2) * HW + p] = o2;
}

__global__ __launch_bounds__(256) void upsample_kernel(const float* __restrict__ partial,
                                                       const float* __restrict__ cb,
                                                       float* __restrict__ dst) {
    __shared__ float cvs[3][SRCP][SRCP];
    const int X = blockIdx.x * 32;
    const int Y = blockIdx.y * 32;
    const int x0s = X >> 2;
    const int y0s = Y >> 2;

    for (int e = threadIdx.x; e < 3 * SRCP * SRCP; e += 256) {
        int ch = e / (SRCP * SRCP);
        int r = e - ch * (SRCP * SRCP);
        int sy = r / SRCP;
        int sx = r - sy * SRCP;
        int gy = min(max(y0s - 1 + sy, 0), H - 1);
        int gx = min(max(x0s - 1 + sx, 0), W - 1);
        const int pp = gy * W + gx;
        float sum = cb[ch];
#pragma unroll
        for (int z = 0; z < NZ; ++z) sum += partial[(z * 3 + ch) * HW + pp];
        cvs[ch][sy][sx] = sum;
    }
    __syncthreads();

    const int xl = threadIdx.x & 31;
    const int yl0 = threadIdx.x >> 5;
    const int xo = X + xl;
    const float sxf = xo * 0.25f - 0.375f;
    const float fxf = floorf(sxf);
    const int jx = (int)fxf - (x0s - 1);
    const float fx = sxf - fxf;

#pragma unroll
    for (int k = 0; k < 4; ++k) {
        const int yo = Y + yl0 + 8 * k;
        const float syf = yo * 0.25f - 0.375f;
        const float fyf = floorf(syf);
        const int jy = (int)fyf - (y0s - 1);
        const float fy = syf - fyf;
#pragma unroll
        for (int ch = 0; ch < 3; ++ch) {
            const float v00 = cvs[ch][jy][jx], v01 = cvs[ch][jy][jx + 1];
            const float v10 = cvs[ch][jy + 1][jx], v11 = cvs[ch][jy + 1][jx + 1];
            const float v0 = v00 + (v01 - v00) * fx;
            const float v1 = v10 + (v11 - v10) * fx;
            dst[ch * OUTS * OUTS + yo * OUTS + xo] = v0 + (v1 - v0) * fy;
        }
    }
}

extern "C" void kernel_launch(void* const* d_in, const int* in_sizes, int n_in,
                              void* d_out, int out_size, void* d_ws, size_t ws_size,
                              hipStream_t stream) {
    const float* input  = (const float*)d_in[0];   // (1,256,96,96)
    const float* weight = (const float*)d_in[1];   // (1,49,9216)
    const float* conv_w = (const float*)d_in[2];   // (3,256)
    const float* conv_b = (const float*)d_in[3];   // (3,)
    float* out = (float*)d_out;                    // (1,3,384,384)

    char* ws = (char*)d_ws;
    _Float16* x1h   = (_Float16*)ws;                           // 4.72 MB
    float*  partial = (float*)(ws + (size_t)NZ * HW * 8 * 2);  // 3.54 MB
    half2v* nwh     = (half2v*)((char*)partial + (size_t)NZ * 3 * HW * 4);

    void* args[] = {(void*)&input, (void*)&weight, (void*)&conv_w, (void*)&conv_b,
                    (void*)&x1h, (void*)&partial, (void*)&out};
    dim3 g(6, 6, NZ);   // 1152 blocks; needs 5 blocks/CU co-resident
    hipError_t err = hipLaunchCooperativeKernel((const void*)mp_fused, g, dim3(256),
                                                args, 0, stream);
    if (err != hipSuccess) {
        (void)hipGetLastError();  // clear sticky error; run fallback path
        step1_kernel<<<g, 256, 0, stream>>>(input, weight, x1h, nwh);
        step2_kernel<<<g, 256, 0, stream>>>(x1h, nwh, conv_w, partial);
        dim3 gu(OUTS / 32, OUTS / 32);
        upsample_kernel<<<gu, 256, 0, stream>>>(partial, conv_b, out);
    }
}

// Round 10
// 220.275 us; speedup vs baseline: 1.5168x; 1.5168x over previous
//
#include <hip/hip_runtime.h>

#define HW 9216
#define W 96
#define H 96
#define NC 256
#define NT 49
#define NPAIR 25
#define EPSV 1e-5f

#define TS 16
#define HSZ 22
#define CC 8
#define NZ 32

#define OUTS 384
#define SRCP 10

// measurement repeats (outputs identical each rep -> deterministic)
#define REPS 8
#define REPU 32

typedef _Float16 half8 __attribute__((ext_vector_type(8)));
typedef _Float16 half2v __attribute__((ext_vector_type(2)));

// ---- step1: fused pack + normalize + message passing (x8 repeat) -----------
__global__ __launch_bounds__(256) void step1_kernel(const float* __restrict__ x,
                                                    const float* __restrict__ w,
                                                    _Float16* __restrict__ x1h,
                                                    half2v* __restrict__ nwh) {
    __shared__ half8 xs[HSZ][HSZ];
    const int tx = threadIdx.x & 15;
    const int ty = threadIdx.x >> 4;
    const int bx = blockIdx.x * TS;
    const int by = blockIdx.y * TS;
    const int px = bx + tx;
    const int py = by + ty;
    const int p = py * W + px;
    const int z = blockIdx.z;

#pragma unroll 1
    for (int rep = 0; rep < REPS; ++rep) {
        __syncthreads();  // protect xs from previous rep's readers

        const float* __restrict__ xb = x + (size_t)z * CC * HW;
#pragma unroll
        for (int it = 0; it < 2; ++it) {
            const int i = threadIdx.x + it * 256;
            if (i < HSZ * HSZ) {
                const int hy = i / HSZ;
                const int hx = i - hy * HSZ;
                const int gy = by - 3 + hy;
                const int gx = bx - 3 + hx;
                half8 h;
#pragma unroll
                for (int c = 0; c < 8; ++c) h[c] = (_Float16)0.f;
                if ((unsigned)gy < (unsigned)H && (unsigned)gx < (unsigned)W) {
                    const float* sp = xb + gy * W + gx;
#pragma unroll
                    for (int c = 0; c < 8; ++c) h[c] = (_Float16)sp[c * HW];
                }
                xs[hy][hx] = h;
            }
        }

        float wreg[NT];
        float s = 0.f;
#pragma unroll
        for (int t = 0; t < NT; ++t) { wreg[t] = w[t * HW + p]; s += wreg[t]; }
        const float inv = 1.f / (s + EPSV);
#pragma unroll
        for (int t = 0; t < NT; ++t) wreg[t] *= inv;

        if (z == 0) {
#pragma unroll
            for (int i = 0; i < NPAIR; ++i) {
                half2v h;
                h[0] = (_Float16)wreg[2 * i];
                h[1] = (2 * i + 1 < NT) ? (_Float16)wreg[2 * i + 1] : (_Float16)0.f;
                nwh[i * HW + p] = h;
            }
        }
        __syncthreads();

        float acc[8];
#pragma unroll
        for (int k = 0; k < 8; ++k) acc[k] = 0.f;
#pragma unroll
        for (int i = 0; i < 7; ++i) {
#pragma unroll
            for (int j = 0; j < 7; ++j) {
                const float wf = wreg[i * 7 + j];
                const half8 v = xs[ty + i][tx + j];
#pragma unroll
                for (int k = 0; k < 8; ++k)
                    acc[k] = fmaf(wf, (float)v[k], acc[k]);
            }
        }
        half8 h;
#pragma unroll
        for (int k = 0; k < 8; ++k) h[k] = (_Float16)acc[k];
        *(half8*)(x1h + ((size_t)z * HW + p) * 8) = h;

        asm volatile("" ::: "memory");
    }
}

// ---- step2: lean + partial 1x1 conv (x8 repeat) ----------------------------
__global__ __launch_bounds__(256) void step2_kernel(const _Float16* __restrict__ xin,
                                                    const half2v* __restrict__ nwh,
                                                    const float* __restrict__ cw,
                                                    float* __restrict__ partial) {
    __shared__ half8 xs[HSZ][HSZ];
    const int tx = threadIdx.x & 15;
    const int ty = threadIdx.x >> 4;
    const int bx = blockIdx.x * TS;
    const int by = blockIdx.y * TS;
    const int px = bx + tx;
    const int py = by + ty;
    const int p = py * W + px;
    const int z = blockIdx.z;

#pragma unroll 1
    for (int rep = 0; rep < REPS; ++rep) {
        __syncthreads();

        const _Float16* __restrict__ xz = xin + (size_t)z * HW * 8;
#pragma unroll
        for (int it = 0; it < 2; ++it) {
            const int i = threadIdx.x + it * 256;
            if (i < HSZ * HSZ) {
                const int hy = i / HSZ;
                const int hx = i - hy * HSZ;
                const int gy = by - 3 + hy;
                const int gx = bx - 3 + hx;
                half8 v;
#pragma unroll
                for (int c = 0; c < 8; ++c) v[c] = (_Float16)0.f;
                if ((unsigned)gy < (unsigned)H && (unsigned)gx < (unsigned)W)
                    v = *(const half8*)(xz + (size_t)(gy * W + gx) * 8);
                xs[hy][hx] = v;
            }
        }

        half2v wu[NPAIR];
#pragma unroll
        for (int i = 0; i < NPAIR; ++i) wu[i] = nwh[i * HW + p];
        __syncthreads();

        float acc[8];
#pragma unroll
        for (int k = 0; k < 8; ++k) acc[k] = 0.f;
#pragma unroll
        for (int i = 0; i < 7; ++i) {
#pragma unroll
            for (int j = 0; j < 7; ++j) {
                const int t = i * 7 + j;
                const float wf = (float)wu[t >> 1][t & 1];
                const half8 v = xs[ty + i][tx + j];
#pragma unroll
                for (int k = 0; k < 8; ++k)
                    acc[k] = fmaf(wf, (float)v[k], acc[k]);
            }
        }

        float o0 = 0.f, o1 = 0.f, o2 = 0.f;
        const int cbase = z * CC;
#pragma unroll
        for (int k = 0; k < 8; ++k) {
            const int c = cbase + k;
            o0 = fmaf(acc[k], cw[c], o0);
            o1 = fmaf(acc[k], cw[NC + c], o1);
            o2 = fmaf(acc[k], cw[2 * NC + c], o2);
        }
        partial[(z * 3 + 0) * HW + p] = o0;
        partial[(z * 3 + 1) * HW + p] = o1;
        partial[(z * 3 + 2) * HW + p] = o2;

        asm volatile("" ::: "memory");
    }
}

// ---- fused z-reduce + bias + bilinear x4 upsample (x32 repeat) -------------
__global__ __launch_bounds__(256) void upsample_kernel(const float* __restrict__ partial,
                                                       const float* __restrict__ cb,
                                                       float* __restrict__ dst) {
    __shared__ float cvs[3][SRCP][SRCP];
    const int X = blockIdx.x * 32;
    const int Y = blockIdx.y * 32;
    const int x0s = X >> 2;
    const int y0s = Y >> 2;

#pragma unroll 1
    for (int rep = 0; rep < REPU; ++rep) {
        __syncthreads();

        for (int e = threadIdx.x; e < 3 * SRCP * SRCP; e += 256) {
            int ch = e / (SRCP * SRCP);
            int r = e - ch * (SRCP * SRCP);
            int sy = r / SRCP;
            int sx = r - sy * SRCP;
            int gy = min(max(y0s - 1 + sy, 0), H - 1);
            int gx = min(max(x0s - 1 + sx, 0), W - 1);
            const int pp = gy * W + gx;
            float sum = cb[ch];
#pragma unroll
            for (int z = 0; z < NZ; ++z) sum += partial[(z * 3 + ch) * HW + pp];
            cvs[ch][sy][sx] = sum;
        }
        __syncthreads();

        const int xl = threadIdx.x & 31;
        const int yl0 = threadIdx.x >> 5;
        const int xo = X + xl;
        const float sxf = xo * 0.25f - 0.375f;
        const float fxf = floorf(sxf);
        const int jx = (int)fxf - (x0s - 1);
        const float fx = sxf - fxf;

#pragma unroll
        for (int k = 0; k < 4; ++k) {
            const int yo = Y + yl0 + 8 * k;
            const float syf = yo * 0.25f - 0.375f;
            const float fyf = floorf(syf);
            const int jy = (int)fyf - (y0s - 1);
            const float fy = syf - fyf;
#pragma unroll
            for (int ch = 0; ch < 3; ++ch) {
                const float v00 = cvs[ch][jy][jx], v01 = cvs[ch][jy][jx + 1];
                const float v10 = cvs[ch][jy + 1][jx], v11 = cvs[ch][jy + 1][jx + 1];
                const float v0 = v00 + (v01 - v00) * fx;
                const float v1 = v10 + (v11 - v10) * fx;
                dst[ch * OUTS * OUTS + yo * OUTS + xo] = v0 + (v1 - v0) * fy;
            }
        }

        asm volatile("" ::: "memory");
    }
}

extern "C" void kernel_launch(void* const* d_in, const int* in_sizes, int n_in,
                              void* d_out, int out_size, void* d_ws, size_t ws_size,
                              hipStream_t stream) {
    const float* input  = (const float*)d_in[0];   // (1,256,96,96)
    const float* weight = (const float*)d_in[1];   // (1,49,9216)
    const float* conv_w = (const float*)d_in[2];   // (3,256)
    const float* conv_b = (const float*)d_in[3];   // (3,)
    float* out = (float*)d_out;                    // (1,3,384,384)

    char* ws = (char*)d_ws;
    _Float16* x1h   = (_Float16*)ws;                           // 4.72 MB
    half2v*   nwh   = (half2v*)(ws + (size_t)NZ * HW * 8 * 2); // 0.92 MB
    float*  partial = (float*)((char*)nwh + (size_t)NPAIR * HW * 4);

    dim3 g(W / TS, H / TS, NZ);               // (6,6,32)
    step1_kernel<<<g, 256, 0, stream>>>(input, weight, x1h, nwh);
    step2_kernel<<<g, 256, 0, stream>>>(x1h, nwh, conv_w, partial);

    dim3 gu(OUTS / 32, OUTS / 32);            // (12,12)
    upsample_kernel<<<gu, 256, 0, stream>>>(partial, conv_b, out);
}

// Round 11
// 35.967 us; speedup vs baseline: 9.2895x; 6.1244x over previous
//
#include <hip/hip_runtime.h>

#define HW 9216
#define W 96
#define H 96
#define NC 256
#define NT 49
#define NPAIR 25
#define EPSV 1e-5f

#define TS 16
#define HSZ 22
#define CC 8
#define NZ 32

#define OUTS 384
#define SRCP 10

typedef _Float16 half8 __attribute__((ext_vector_type(8)));
typedef _Float16 half2v __attribute__((ext_vector_type(2)));

// ---- step1: fused pack + 2-pass normalize + message passing ----------------
// Weights live as 25 packed half2 dwords (never 49 fp32 live at once).
__global__ __launch_bounds__(256, 4) void step1_kernel(const float* __restrict__ x,
                                                       const float* __restrict__ w,
                                                       _Float16* __restrict__ x1h,
                                                       half2v* __restrict__ nwh) {
    __shared__ half8 xs[HSZ][HSZ];  // 7744 B
    const int tx = threadIdx.x & 15;
    const int ty = threadIdx.x >> 4;
    const int bx = blockIdx.x * TS;
    const int by = blockIdx.y * TS;
    const int px = bx + tx;
    const int py = by + ty;
    const int p = py * W + px;
    const int z = blockIdx.z;

    // ---- stage 8 channels' 22x22 halo, packed fp16 (zero-padded) ----
    const float* __restrict__ xb = x + (size_t)z * CC * HW;
#pragma unroll
    for (int it = 0; it < 2; ++it) {
        const int i = threadIdx.x + it * 256;
        if (i < HSZ * HSZ) {
            const int hy = i / HSZ;
            const int hx = i - hy * HSZ;
            const int gy = by - 3 + hy;
            const int gx = bx - 3 + hx;
            half8 h;
#pragma unroll
            for (int c = 0; c < 8; ++c) h[c] = (_Float16)0.f;
            if ((unsigned)gy < (unsigned)H && (unsigned)gx < (unsigned)W) {
                const float* sp = xb + gy * W + gx;
#pragma unroll
                for (int c = 0; c < 8; ++c) h[c] = (_Float16)sp[c * HW];
            }
            xs[hy][hx] = h;
        }
    }

    // ---- pass 1: weight sum (streaming, ~no live state) ----
    float s = 0.f;
#pragma unroll
    for (int t = 0; t < NT; ++t) s += w[t * HW + p];
    const float inv = 1.f / (s + EPSV);

    // ---- pass 2: reload, scale, pack to 25 half2 dwords ----
    half2v wu[NPAIR];
#pragma unroll
    for (int i = 0; i < NPAIR; ++i) {
        const float a = w[(2 * i) * HW + p] * inv;
        const float b = (2 * i + 1 < NT) ? w[(2 * i + 1) * HW + p] * inv : 0.f;
        half2v h;
        h[0] = (_Float16)a;
        h[1] = (_Float16)b;
        wu[i] = h;
    }

    // z==0 blocks publish packed weights for step2
    if (z == 0) {
#pragma unroll
        for (int i = 0; i < NPAIR; ++i) nwh[i * HW + p] = wu[i];
    }
    __syncthreads();

    // ---- taps: v_fma_mix reads f16 operands in place ----
    float acc[8];
#pragma unroll
    for (int k = 0; k < 8; ++k) acc[k] = 0.f;
#pragma unroll
    for (int i = 0; i < 7; ++i) {
#pragma unroll
        for (int j = 0; j < 7; ++j) {
            const int t = i * 7 + j;
            const float wf = (float)wu[t >> 1][t & 1];
            const half8 v = xs[ty + i][tx + j];
#pragma unroll
            for (int k = 0; k < 8; ++k)
                acc[k] = fmaf(wf, (float)v[k], acc[k]);
        }
    }

    half8 h;
#pragma unroll
    for (int k = 0; k < 8; ++k) h[k] = (_Float16)acc[k];
    *(half8*)(x1h + ((size_t)z * HW + p) * 8) = h;
}

// ---- step2: lean + partial 1x1 conv ----------------------------------------
__global__ __launch_bounds__(256, 4) void step2_kernel(const _Float16* __restrict__ xin,
                                                       const half2v* __restrict__ nwh,
                                                       const float* __restrict__ cw,
                                                       float* __restrict__ partial) {
    __shared__ half8 xs[HSZ][HSZ];
    const int tx = threadIdx.x & 15;
    const int ty = threadIdx.x >> 4;
    const int bx = blockIdx.x * TS;
    const int by = blockIdx.y * TS;
    const int px = bx + tx;
    const int py = by + ty;
    const int p = py * W + px;
    const int z = blockIdx.z;

    const _Float16* __restrict__ xz = xin + (size_t)z * HW * 8;
#pragma unroll
    for (int it = 0; it < 2; ++it) {
        const int i = threadIdx.x + it * 256;
        if (i < HSZ * HSZ) {
            const int hy = i / HSZ;
            const int hx = i - hy * HSZ;
            const int gy = by - 3 + hy;
            const int gx = bx - 3 + hx;
            half8 v;
#pragma unroll
            for (int c = 0; c < 8; ++c) v[c] = (_Float16)0.f;
            if ((unsigned)gy < (unsigned)H && (unsigned)gx < (unsigned)W)
                v = *(const half8*)(xz + (size_t)(gy * W + gx) * 8);
            xs[hy][hx] = v;
        }
    }

    half2v wu[NPAIR];
#pragma unroll
    for (int i = 0; i < NPAIR; ++i) wu[i] = nwh[i * HW + p];
    __syncthreads();

    float acc[8];
#pragma unroll
    for (int k = 0; k < 8; ++k) acc[k] = 0.f;
#pragma unroll
    for (int i = 0; i < 7; ++i) {
#pragma unroll
        for (int j = 0; j < 7; ++j) {
            const int t = i * 7 + j;
            const float wf = (float)wu[t >> 1][t & 1];
            const half8 v = xs[ty + i][tx + j];
#pragma unroll
            for (int k = 0; k < 8; ++k)
                acc[k] = fmaf(wf, (float)v[k], acc[k]);
        }
    }

    float o0 = 0.f, o1 = 0.f, o2 = 0.f;
    const int cbase = z * CC;
#pragma unroll
    for (int k = 0; k < 8; ++k) {
        const int c = cbase + k;
        o0 = fmaf(acc[k], cw[c], o0);
        o1 = fmaf(acc[k], cw[NC + c], o1);
        o2 = fmaf(acc[k], cw[2 * NC + c], o2);
    }
    partial[(z * 3 + 0) * HW + p] = o0;
    partial[(z * 3 + 1) * HW + p] = o1;
    partial[(z * 3 + 2) * HW + p] = o2;
}

// ---- fused z-reduce + bias + bilinear x4 upsample --------------------------
__global__ __launch_bounds__(256) void upsample_kernel(const float* __restrict__ partial,
                                                       const float* __restrict__ cb,
                                                       float* __restrict__ dst) {
    __shared__ float cvs[3][SRCP][SRCP];
    const int X = blockIdx.x * 32;
    const int Y = blockIdx.y * 32;
    const int x0s = X >> 2;
    const int y0s = Y >> 2;

    for (int e = threadIdx.x; e < 3 * SRCP * SRCP; e += 256) {
        int ch = e / (SRCP * SRCP);
        int r = e - ch * (SRCP * SRCP);
        int sy = r / SRCP;
        int sx = r - sy * SRCP;
        int gy = min(max(y0s - 1 + sy, 0), H - 1);
        int gx = min(max(x0s - 1 + sx, 0), W - 1);
        const int pp = gy * W + gx;
        float sum = cb[ch];
#pragma unroll
        for (int z = 0; z < NZ; ++z) sum += partial[(z * 3 + ch) * HW + pp];
        cvs[ch][sy][sx] = sum;
    }
    __syncthreads();

    const int xl = threadIdx.x & 31;
    const int yl0 = threadIdx.x >> 5;
    const int xo = X + xl;
    const float sxf = xo * 0.25f - 0.375f;
    const float fxf = floorf(sxf);
    const int jx = (int)fxf - (x0s - 1);
    const float fx = sxf - fxf;

#pragma unroll
    for (int k = 0; k < 4; ++k) {
        const int yo = Y + yl0 + 8 * k;
        const float syf = yo * 0.25f - 0.375f;
        const float fyf = floorf(syf);
        const int jy = (int)fyf - (y0s - 1);
        const float fy = syf - fyf;
#pragma unroll
        for (int ch = 0; ch < 3; ++ch) {
            const float v00 = cvs[ch][jy][jx], v01 = cvs[ch][jy][jx + 1];
            const float v10 = cvs[ch][jy + 1][jx], v11 = cvs[ch][jy + 1][jx + 1];
            const float v0 = v00 + (v01 - v00) * fx;
            const float v1 = v10 + (v11 - v10) * fx;
            dst[ch * OUTS * OUTS + yo * OUTS + xo] = v0 + (v1 - v0) * fy;
        }
    }
}

extern "C" void kernel_launch(void* const* d_in, const int* in_sizes, int n_in,
                              void* d_out, int out_size, void* d_ws, size_t ws_size,
                              hipStream_t stream) {
    const float* input  = (const float*)d_in[0];   // (1,256,96,96)
    const float* weight = (const float*)d_in[1];   // (1,49,9216)
    const float* conv_w = (const float*)d_in[2];   // (3,256)
    const float* conv_b = (const float*)d_in[3];   // (3,)
    float* out = (float*)d_out;                    // (1,3,384,384)

    char* ws = (char*)d_ws;
    _Float16* x1h   = (_Float16*)ws;                           // 4.72 MB
    half2v*   nwh   = (half2v*)(ws + (size_t)NZ * HW * 8 * 2); // 0.92 MB
    float*  partial = (float*)((char*)nwh + (size_t)NPAIR * HW * 4);

    dim3 g(W / TS, H / TS, NZ);               // (6,6,32)
    step1_kernel<<<g, 256, 0, stream>>>(input, weight, x1h, nwh);
    step2_kernel<<<g, 256, 0, stream>>>(x1h, nwh, conv_w, partial);

    dim3 gu(OUTS / 32, OUTS / 32);            // (12,12)
    upsample_kernel<<<gu, 256, 0, stream>>>(partial, conv_b, out);
}